// Round 3
// baseline (326.804 us; speedup 1.0000x reference)
//
#include <hip/hip_runtime.h>
#include <hip/hip_bf16.h>
#include <math.h>

typedef __hip_bfloat16 bf16;
typedef __attribute__((ext_vector_type(8))) __bf16 bf16x8;
typedef __attribute__((ext_vector_type(4))) float f32x4;
typedef unsigned int u32x4 __attribute__((ext_vector_type(4)));
typedef unsigned int u32x2 __attribute__((ext_vector_type(2)));

#define F_IN 64
#define KNB 6

// ws float offsets: biases + flags + frag blobs; staged xp/xs after STAGE_OFF
#define WOFF_BP   2048   // 32
#define WOFF_BE2  9472   // 32
#define WOFF_BE3  9696   // 6
#define WOFF_BS1  11776  // 32
#define WOFF_BS2  12832  // 32
#define WOFF_BS3  12896  // 1
#define FLAGS_OFF 13056  // int[2]: {is_bf16, is_int64}
#define FRAG_OFF  14592  // 30 frags * 256 floats = 7680 -> ends 22272
#define NFRAG_PRE 11
#define NFRAG_EDGE 19
#define STAGE_OFF 24576  // floats; then xp bf16 rows, then xs fp32

#define MFMA(a, b, c) __builtin_amdgcn_mfma_f32_16x16x32_bf16(a, b, c, 0, 0, 0)

__device__ __forceinline__ float b2f(bf16 v) { return __bfloat162float(v); }
// fast ELU via hardware exp; abs err ~1e-7 near 0, far under tol
__device__ __forceinline__ float eluf(float v) { return v > 0.f ? v : __expf(v) - 1.f; }

__device__ __forceinline__ ushort f2bu(float v) {
  __bf16 b = (__bf16)v; ushort u; __builtin_memcpy(&u, &b, 2); return u;
}

union U8 { uint4 u; bf16x8 v; ushort s[8]; };

// non-temporal loads (read-once streaming data; keep L2/L3 for xp gathers)
__device__ __forceinline__ uint4 ntload16(const void* p) {
  u32x4 t = __builtin_nontemporal_load((const u32x4*)p);
  uint4 r; r.x = t.x; r.y = t.y; r.z = t.z; r.w = t.w; return r;
}
__device__ __forceinline__ uint2 ntload8(const void* p) {
  u32x2 t = __builtin_nontemporal_load((const u32x2*)p);
  uint2 r; r.x = t.x; r.y = t.y; return r;
}

// read one staged weight A-fragment (1KB blob: lane*16B) from LDS
__device__ __forceinline__ bf16x8 ldfrag(const ushort* fr, int f) {
  U8 u; u.u = *(const uint4*)(fr + f * 512 + (threadIdx.x & 63) * 8);
  return u.v;
}

// permuted output-feature index: C row m' of half t holds original feature o.
// Makes the transposed-MFMA C layout coincide with the next layer's B-frag layout.
__device__ __forceinline__ int permo(int m, int t) { return 8 * (m >> 2) + (m & 3) + 4 * t; }

// ==================== setup: flags + bias staging + frag build (parallel, raw-source) ====================
__global__ void setupK(const ushort* xb, const int* ni,
                       const void* Wp, const void* bp, const void* We1, const void* be1,
                       const void* We2, const void* be2, const void* We3, const void* be3,
                       const void* Ws1, const void* bs1, const void* Ws2, const void* bs2,
                       const void* Ws3, const void* bs3, float* w) {
  __shared__ int sbf;
  int t = threadIdx.x;
  // per-block dtype detect (cheap, L2-hot): fp32 bits read as bf16 halves are wild
  if (t < 64) {
    int bad = 0;
    for (int i = t; i < 256; i += 64) {
      float v = __uint_as_float(((unsigned)xb[i]) << 16);
      if (!(fabsf(v) < 100.f)) bad++;
    }
    unsigned long long bm = __ballot(bad > 0);
    if (t == 0) sbf = (__popcll(bm) < 4) ? 1 : 0;
  }
  __syncthreads();
  int bf = sbf;
  auto rv = [&](const void* p, long i) -> float {
    return bf ? b2f(((const bf16*)p)[i]) : ((const float*)p)[i];
  };
  if (blockIdx.x == 0) {
    if (t < 64) {
      unsigned long long hm = __ballot(ni[2 * t + 1] != 0);
      if (t == 0) {
        ((int*)(w + FLAGS_OFF))[0] = bf;
        ((int*)(w + FLAGS_OFF))[1] = (hm == 0ULL) ? 1 : 0;
      }
    }
    const void* bsrc[6] = {bp, bs1, bs2, bs3, be2, be3};
    const int bn[6] = {32, 32, 32, 1, 32, 6};
    const int bo[6] = {WOFF_BP, WOFF_BS1, WOFF_BS2, WOFF_BS3, WOFF_BE2, WOFF_BE3};
    for (int a = 0; a < 6; a++)
      for (int i = t; i < bn[a]; i += blockDim.x)
        w[bo[a] + i] = rv(bsrc[a], i);
  }
  // Frag element layout: blob[lane*8 + j] = A[m=lane&15][k=8*(lane>>4)+j].
  // ids: 0..3 P[s][t], 4..7 S1[s][t], 8..9 S2[t], 10 S3,
  //      11..22 E1[kn][t] (negated), 23..24 ESUM[t], 25..26 EDSQ[t] (+be1 row),
  //      27..28 E2[t], 29 E3
  ushort* fbv = (ushort*)(w + FRAG_OFF);
  int total = (NFRAG_PRE + NFRAG_EDGE) * 512;
  for (int i = blockIdx.x * blockDim.x + t; i < total; i += gridDim.x * blockDim.x) {
    int f = i >> 9, e = i & 511;
    int lane = e >> 3, j = e & 7;
    int mm = lane & 15, qq = lane >> 4;
    int k = qq * 8 + j;
    float v = 0.f;
    if (f < 4) { int s = f >> 1, tt = f & 1; v = rv(Wp, (long)(32 * s + k) * 32 + permo(mm, tt)); }
    else if (f < 8) { int s = (f - 4) >> 1, tt = f & 1; v = rv(Ws1, (long)(32 * s + k) * 32 + permo(mm, tt)); }
    else if (f < 10) { int tt = f & 1; v = rv(Ws2, (long)k * 32 + permo(mm, tt)); }
    else if (f == 10) { v = (mm == 0) ? rv(Ws3, k) : 0.f; }
    else if (f < 23) { int kn = (f - 11) >> 1, tt = (f - 11) & 1;
                       v = -rv(We1, (long)(kn * 33 + k) * 32 + permo(mm, tt)); }
    else if (f < 25) { int tt = f - 23; float s = 0.f;
#pragma unroll
                       for (int kn = 0; kn < KNB; kn++)
                         s += rv(We1, (long)(kn * 33 + k) * 32 + permo(mm, tt));
                       v = s; }
    else if (f < 27) { int tt = f - 25; int o = permo(mm, tt);
                       v = (k < 6) ? rv(We1, (long)(k * 33 + 32) * 32 + o)
                                   : (k == 6 ? rv(be1, o) : 0.f); }
    else if (f < 29) { int tt = f - 27; v = rv(We2, (long)k * 32 + permo(mm, tt)); }
    else { v = (mm < KNB) ? rv(We3, (long)k * 6 + mm) : 0.f; }
    fbv[i] = f2bu(v);
  }
}

// ==================== kernel A: pre-dense + self MLP (transposed MFMA, no LDS data) ====================
template <bool BF16>
__device__ void pre_tiles(const void* xv, const float* __restrict__ w,
                          ushort* __restrict__ xp, float* __restrict__ xs,
                          int n_nodes, const ushort* __restrict__ fr) {
  int lane = threadIdx.x & 63;
  int m = lane & 15, q = lane >> 4;
  float bp8[8], bs18[8], bs28[8];
#pragma unroll
  for (int j = 0; j < 8; j++) {
    bp8[j]  = w[WOFF_BP  + 8 * q + j];
    bs18[j] = w[WOFF_BS1 + 8 * q + j];
    bs28[j] = w[WOFF_BS2 + 8 * q + j];
  }
  float bs3 = w[WOFF_BS3];
  long T = ((long)n_nodes + 15) >> 4;
  long wid = (long)((blockIdx.x * blockDim.x + threadIdx.x) >> 6);
  long nw = (long)((gridDim.x * blockDim.x) >> 6);
  f32x4 zero = {0.f, 0.f, 0.f, 0.f};

  uint4 bufA[4], bufB[4];
  auto loadraw = [&](uint4* r, long tt) {
    long row = tt * 16 + m; if (row >= n_nodes) row = n_nodes - 1;
    if (BF16) {
      const ushort* p = (const ushort*)xv + row * F_IN + q * 8;
      r[0] = ntload16(p);
      r[1] = ntload16(p + 32);
    } else {
      const float* p = (const float*)xv + row * F_IN + q * 8;
      r[0] = ntload16(p);      r[1] = ntload16(p + 4);
      r[2] = ntload16(p + 32); r[3] = ntload16(p + 36);
    }
  };
  auto mkfrag = [&](const uint4* r, int s) -> bf16x8 {
    if (BF16) { U8 u; u.u = r[s]; return u.v; }
    float f0[8];
    __builtin_memcpy(f0, r + 2 * s, 32);
    bf16x8 out;
#pragma unroll
    for (int j = 0; j < 8; j++) out[j] = (__bf16)f0[j];
    return out;
  };
  auto body = [&](uint4* cur, uint4* nxt, long t) {
    long tn = t + nw;
    if (tn < T) loadraw(nxt, tn);            // prefetch next tile's x
    long n0 = t * 16;
    long row = n0 + m; if (row >= n_nodes) row = n_nodes - 1;
    bf16x8 x0 = mkfrag(cur, 0), x1 = mkfrag(cur, 1);
    f32x4 aP[2], aS[2];
    __builtin_amdgcn_s_setprio(1);
#pragma unroll
    for (int tt = 0; tt < 2; tt++) {
      aP[tt] = MFMA(ldfrag(fr, 0 + tt), x0, zero);
      aP[tt] = MFMA(ldfrag(fr, 2 + tt), x1, aP[tt]);
      aS[tt] = MFMA(ldfrag(fr, 4 + tt), x0, zero);
      aS[tt] = MFMA(ldfrag(fr, 6 + tt), x1, aS[tt]);
    }
    __builtin_amdgcn_s_setprio(0);
    // xp row store straight from registers: lane holds features 8q..8q+7 of its node
    U8 o1;
#pragma unroll
    for (int j = 0; j < 8; j++) o1.s[j] = f2bu(eluf(aP[j >> 2][j & 3] + bp8[j]));
    *(uint4*)(xp + row * 32 + q * 8) = o1.u;
    bf16x8 s1e;
#pragma unroll
    for (int j = 0; j < 8; j++) s1e[j] = (__bf16)eluf(aS[j >> 2][j & 3] + bs18[j]);
    f32x4 a2[2];
#pragma unroll
    for (int tt = 0; tt < 2; tt++) a2[tt] = MFMA(ldfrag(fr, 8 + tt), s1e, zero);
    bf16x8 s2e;
#pragma unroll
    for (int j = 0; j < 8; j++) s2e[j] = (__bf16)eluf(a2[j >> 2][j & 3] + bs28[j]);
    f32x4 a3 = MFMA(ldfrag(fr, 10), s2e, zero);
    if (q == 0) {
      long orow = n0 + m;
      if (orow < n_nodes) xs[orow] = a3[0] + bs3;
    }
  };
  long t = wid;
  if (t < T) loadraw(bufA, t);
  while (t < T) {
    body(bufA, bufB, t);
    t += nw; if (t >= T) break;
    body(bufB, bufA, t);
    t += nw;
  }
}

__launch_bounds__(256, 4)
__global__ void preK(const void* xv, const float* __restrict__ w,
                     const int* __restrict__ flags,
                     ushort* __restrict__ xp, float* __restrict__ xs, int n_nodes) {
  __shared__ uint4 fsh[NFRAG_PRE * 64];
  const uint4* fbv = (const uint4*)((const ushort*)(w + FRAG_OFF));
  for (int i = threadIdx.x; i < NFRAG_PRE * 64; i += blockDim.x) fsh[i] = fbv[i];
  __syncthreads();
  const ushort* fr = (const ushort*)fsh;
  if (flags[0]) pre_tiles<true>(xv, w, xp, xs, n_nodes, fr);
  else          pre_tiles<false>(xv, w, xp, xs, n_nodes, fr);
}

// ==================== kernel B: edge MLP + softmax (transposed MFMA, depth-2 pipeline) ====================
struct ETile { U8 nb[KNB]; U8 own; U8 ad; float xsv; };

template <bool BF16>
__device__ void edge_tiles(const ushort* __restrict__ xp, const float* __restrict__ xs,
                           const void* dsv, const int* __restrict__ ni, int i64,
                           const float* __restrict__ w, void* outv, int n_nodes,
                           const ushort* __restrict__ fr) {
  int lane = threadIdx.x & 63;
  int m = lane & 15, q = lane >> 4;
  float b2[8], b3[4];
#pragma unroll
  for (int j = 0; j < 8; j++) b2[j] = w[WOFF_BE2 + 8 * q + j];
#pragma unroll
  for (int r = 0; r < 4; r++) { int o = 4 * q + r; b3[r] = (o < 6) ? w[WOFF_BE3 + o] : 0.f; }

  long T = ((long)n_nodes + 15) >> 4;
  long wid = (long)((blockIdx.x * blockDim.x + threadIdx.x) >> 6);
  long nw = (long)((gridDim.x * blockDim.x) >> 6);
  f32x4 zero = {0.f, 0.f, 0.f, 0.f};
  ETile A, B;
  int Ia[KNB], Ib[KNB];

  // neighbor indices for tile tt (vectorized, non-temporal; used one body later)
  auto pidx = [&](int* ix, long tt) {
    long row = tt * 16 + m; if (row >= n_nodes) row = n_nodes - 1;
    if (i64) {
      const uint4* p = (const uint4*)((const char*)ni + row * (KNB * 8));  // 16B aligned
      uint4 a = ntload16(p), b = ntload16(p + 1), c = ntload16(p + 2);
      ix[0] = (int)a.x; ix[1] = (int)a.z; ix[2] = (int)b.x;
      ix[3] = (int)b.z; ix[4] = (int)c.x; ix[5] = (int)c.z;
    } else {
      const uint2* p = (const uint2*)((const char*)ni + row * (KNB * 4));  // 8B aligned
      uint2 a = ntload8(p), b = ntload8(p + 1), c = ntload8(p + 2);
      ix[0] = (int)a.x; ix[1] = (int)a.y; ix[2] = (int)b.x;
      ix[3] = (int)b.y; ix[4] = (int)c.x; ix[5] = (int)c.y;
    }
  };
  // streaming per-node loads (own xp row, distsq, xs)
  auto phead = [&](ETile& d, long tt) {
    long row = tt * 16 + m; if (row >= n_nodes) row = n_nodes - 1;
    d.own.u = *(const uint4*)(xp + row * 32 + q * 8);
    d.ad.u.x = 0; d.ad.u.y = 0; d.ad.u.z = 0; d.ad.u.w = 0;
    if (q == 0) {
      if (BF16) {
        const unsigned* dp = (const unsigned*)dsv;
        d.ad.u.x = dp[row * 3 + 0]; d.ad.u.y = dp[row * 3 + 1]; d.ad.u.z = dp[row * 3 + 2];
      } else {
        const uint2* dp = (const uint2*)((const char*)dsv + row * (KNB * 4));
        uint2 a = ntload8(dp), b = ntload8(dp + 1), c = ntload8(dp + 2);
        d.ad.s[0] = f2bu(__uint_as_float(a.x)); d.ad.s[1] = f2bu(__uint_as_float(a.y));
        d.ad.s[2] = f2bu(__uint_as_float(b.x)); d.ad.s[3] = f2bu(__uint_as_float(b.y));
        d.ad.s[4] = f2bu(__uint_as_float(c.x)); d.ad.s[5] = f2bu(__uint_as_float(c.y));
      }
      d.ad.s[6] = 0x3F80u;  // 1.0bf16: multiplies the be1 row baked into EDSQ frag
    }
    d.xsv = xs[row];
  };
  // dependent random gathers (indices issued one full body earlier)
  auto pgather = [&](ETile& d, const int* ix) {
#pragma unroll
    for (int k = 0; k < KNB; k++) {
      int v = ix[k];
      long ai = (v < 0 || v >= n_nodes) ? 0 : (long)v;
      uint4 g = *(const uint4*)(xp + ai * 32 + q * 8);
      if (v < 0) { g.x = 0; g.y = 0; g.z = 0; g.w = 0; }
      d.nb[k].u = g;
    }
  };
  auto iterb = [&](ETile& cur, ETile& nxt, int* Iin, int* Iout, long t) {
    long t2 = t + 2 * nw;
    bool h2 = t2 < T;
    if (t + nw < T) pgather(nxt, Iin);      // gathers for t+1: hidden under whole body
    if (h2) pidx(Iout, t2);                 // indices two tiles ahead
    // layer 1: h1^T = ESUM*own + EDSQ*[dsq,1] + sum_k (-E1k)*nb_k (be1 folded in EDSQ)
    f32x4 acc[2];
    __builtin_amdgcn_s_setprio(1);
#pragma unroll
    for (int tt = 0; tt < 2; tt++) {
      acc[tt] = MFMA(ldfrag(fr, 12 + tt), cur.own.v, zero);
      acc[tt] = MFMA(ldfrag(fr, 14 + tt), cur.ad.v, acc[tt]);
#pragma unroll
      for (int k = 0; k < KNB; k++)
        acc[tt] = MFMA(ldfrag(fr, k * 2 + tt), cur.nb[k].v, acc[tt]);
    }
    __builtin_amdgcn_s_setprio(0);
    // layers 2/3 entirely in registers (perm baked into frags)
    bf16x8 a1;
#pragma unroll
    for (int j = 0; j < 8; j++) a1[j] = (__bf16)eluf(acc[j >> 2][j & 3]);
    f32x4 acc2[2];
    __builtin_amdgcn_s_setprio(1);
#pragma unroll
    for (int tt = 0; tt < 2; tt++) acc2[tt] = MFMA(ldfrag(fr, 16 + tt), a1, zero);
    __builtin_amdgcn_s_setprio(0);
    bf16x8 a2;
#pragma unroll
    for (int j = 0; j < 8; j++) a2[j] = (__bf16)eluf(acc2[j >> 2][j & 3] + b2[j]);
    f32x4 a3 = MFMA(ldfrag(fr, 18), a2, zero);
    float l0 = a3[0] + b3[0], l1 = a3[1] + b3[1], l2 = a3[2] + b3[2], l3 = a3[3] + b3[3];
    // quad1 holds logits 4,5 for the same node; pull them to quad0
    float o4 = __shfl(l0, m + 16, 64);
    float o5 = __shfl(l1, m + 16, 64);
    if (lane < 16) {
      long nodeid = t * 16 + lane;
      if (nodeid < n_nodes) {
        float lg[7] = {cur.xsv, l0, l1, l2, l3, o4, o5};
        float mx = lg[0];
#pragma unroll
        for (int i = 1; i < 7; i++) mx = fmaxf(mx, lg[i]);
        float e[7], ssum = 0.f;
#pragma unroll
        for (int i = 0; i < 7; i++) { e[i] = __expf(lg[i] - mx); ssum += e[i]; }
        float inv = 1.f / ssum;
        if (BF16) {
          ushort* o = (ushort*)outv + nodeid * 7;
#pragma unroll
          for (int i = 0; i < 7; i++) __builtin_nontemporal_store(f2bu(e[i] * inv), o + i);
        } else {
          float* o = (float*)outv + nodeid * 7;
#pragma unroll
          for (int i = 0; i < 7; i++) __builtin_nontemporal_store(e[i] * inv, o + i);
        }
      }
    }
    if (h2) phead(cur, t2);                 // reuse cur slot: head of tile t+2
  };
  long t = wid;
  if (t < T) {
    pidx(Ia, t); phead(A, t); pgather(A, Ia);
    if (t + nw < T) { pidx(Ia, t + nw); phead(B, t + nw); }
  }
  while (t < T) {
    iterb(A, B, Ia, Ib, t);
    t += nw; if (t >= T) break;
    iterb(B, A, Ib, Ia, t);
    t += nw;
  }
}

__launch_bounds__(256, 4)
__global__ void edgeK(const ushort* __restrict__ xp, const float* __restrict__ xs,
                      const void* dsv, const int* __restrict__ ni,
                      const float* __restrict__ w, const int* __restrict__ flags,
                      void* outv, int n_nodes) {
  __shared__ uint4 fsh[NFRAG_EDGE * 64];
  const uint4* fbv = (const uint4*)((const ushort*)(w + FRAG_OFF) + NFRAG_PRE * 512);
  for (int i = threadIdx.x; i < NFRAG_EDGE * 64; i += blockDim.x) fsh[i] = fbv[i];
  __syncthreads();
  const ushort* fr = (const ushort*)fsh;
  if (flags[0]) edge_tiles<true>(xp, xs, dsv, ni, flags[1], w, outv, n_nodes, fr);
  else          edge_tiles<false>(xp, xs, dsv, ni, flags[1], w, outv, n_nodes, fr);
}

// ==================== fallback path (small ws) ====================
template <bool BF16>
__device__ __forceinline__ float wval(const void* W, long i) {
  if (BF16) return b2f(((const bf16*)W)[i]);
  return ((const float*)W)[i];
}

__device__ __forceinline__ void block_flags(const ushort* xb, const int* ni, int* sflags) {
  if (threadIdx.x < 64) {
    int t = threadIdx.x;
    int bad = 0;
    for (int i = t; i < 256; i += 64) {
      float v = __uint_as_float(((unsigned)xb[i]) << 16);
      if (!(fabsf(v) < 100.f)) bad++;
    }
    unsigned long long bm = __ballot(bad > 0);
    unsigned long long hm = __ballot(ni[2 * t + 1] != 0);
    if (t == 0) {
      sflags[0] = (__popcll(bm) < 4) ? 1 : 0;
      sflags[1] = (hm == 0ULL) ? 1 : 0;
    }
  }
  __syncthreads();
}

template <bool BF16>
__device__ void node_body(int n, int n_nodes, const void* xv, const void* dsv,
                          const int* __restrict__ ni, int i64,
                          const void* Wp, const void* bp, const void* We1, const void* be1,
                          const void* We2, const void* be2, const void* We3, const void* be3,
                          const void* Ws1, const void* bs1, const void* Ws2, const void* bs2,
                          const void* Ws3, const void* bs3, void* outv) {
  float h[32], s1[32];
#pragma unroll
  for (int o = 0; o < 32; o++) { h[o] = wval<BF16>(bp, o); s1[o] = wval<BF16>(bs1, o); }
  for (int j = 0; j < F_IN; j++) {
    float xj = wval<BF16>(xv, (long)n * F_IN + j);
#pragma unroll
    for (int o = 0; o < 32; o++) {
      h[o]  += xj * wval<BF16>(Wp,  (long)j * 32 + o);
      s1[o] += xj * wval<BF16>(Ws1, (long)j * 32 + o);
    }
  }
  float own[32];
#pragma unroll
  for (int o = 0; o < 32; o++) own[o] = eluf(h[o]);
  float s2[32];
#pragma unroll
  for (int o = 0; o < 32; o++) s2[o] = wval<BF16>(bs2, o);
  for (int j = 0; j < 32; j++) {
    float v = eluf(s1[j]);
#pragma unroll
    for (int o = 0; o < 32; o++) s2[o] += v * wval<BF16>(Ws2, (long)j * 32 + o);
  }
  float xsv = wval<BF16>(bs3, 0);
#pragma unroll
  for (int j = 0; j < 32; j++) xsv += eluf(s2[j]) * wval<BF16>(Ws3, j);

  float h1[32];
#pragma unroll
  for (int o = 0; o < 32; o++) h1[o] = wval<BF16>(be1, o);
  for (int k = 0; k < KNB; k++) {
    long pos = (long)n * KNB + k;
    int idx = i64 ? ni[2 * pos] : ni[pos];
    float mmask = idx < 0 ? 0.f : 1.f;
    long ai = idx < 0 ? 0 : idx;
    if (ai >= n_nodes) ai = 0;
    float nh[32];
#pragma unroll
    for (int o = 0; o < 32; o++) nh[o] = wval<BF16>(bp, o);
    for (int j = 0; j < F_IN; j++) {
      float xj = wval<BF16>(xv, ai * F_IN + j);
#pragma unroll
      for (int o = 0; o < 32; o++) nh[o] += xj * wval<BF16>(Wp, (long)j * 32 + o);
    }
#pragma unroll
    for (int j = 0; j < 32; j++) {
      float d = own[j] - mmask * eluf(nh[j]);
#pragma unroll
      for (int o = 0; o < 32; o++) h1[o] += d * wval<BF16>(We1, ((long)(k * 33 + j)) * 32 + o);
    }
    float dsq = BF16 ? b2f(((const bf16*)dsv)[pos]) : ((const float*)dsv)[pos];
#pragma unroll
    for (int o = 0; o < 32; o++) h1[o] += dsq * wval<BF16>(We1, ((long)(k * 33 + 32)) * 32 + o);
  }
  float h2[32];
#pragma unroll
  for (int o = 0; o < 32; o++) h2[o] = wval<BF16>(be2, o);
  for (int j = 0; j < 32; j++) {
    float v = eluf(h1[j]);
#pragma unroll
    for (int o = 0; o < 32; o++) h2[o] += v * wval<BF16>(We2, (long)j * 32 + o);
  }
  float lg[7];
  lg[0] = xsv;
#pragma unroll
  for (int o = 0; o < 6; o++) lg[1 + o] = wval<BF16>(be3, o);
  for (int j = 0; j < 32; j++) {
    float v = eluf(h2[j]);
#pragma unroll
    for (int o = 0; o < 6; o++) lg[1 + o] += v * wval<BF16>(We3, (long)j * 6 + o);
  }
  float mx = lg[0];
#pragma unroll
  for (int i = 1; i < 7; i++) mx = fmaxf(mx, lg[i]);
  float e[7], ssum = 0.f;
#pragma unroll
  for (int i = 0; i < 7; i++) { e[i] = __expf(lg[i] - mx); ssum += e[i]; }
  float inv = 1.f / ssum;
  if (BF16) {
    bf16* o = (bf16*)outv;
#pragma unroll
    for (int i = 0; i < 7; i++) o[(long)n * 7 + i] = __float2bfloat16(e[i] * inv);
  } else {
    float* o = (float*)outv;
#pragma unroll
    for (int i = 0; i < 7; i++) o[(long)n * 7 + i] = e[i] * inv;
  }
}

__launch_bounds__(256)
__global__ void fused(const void* xv, const void* dsv, const int* __restrict__ ni,
                      const void* Wp, const void* bp, const void* We1, const void* be1,
                      const void* We2, const void* be2, const void* We3, const void* be3,
                      const void* Ws1, const void* bs1, const void* Ws2, const void* bs2,
                      const void* Ws3, const void* bs3, void* outv, int n_nodes) {
  __shared__ int sflags[2];
  block_flags((const ushort*)xv, ni, sflags);
  int n = blockIdx.x * blockDim.x + threadIdx.x;
  if (n >= n_nodes) return;
  if (sflags[0]) node_body<true>(n, n_nodes, xv, dsv, ni, sflags[1], Wp, bp, We1, be1,
                                 We2, be2, We3, be3, Ws1, bs1, Ws2, bs2, Ws3, bs3, outv);
  else           node_body<false>(n, n_nodes, xv, dsv, ni, sflags[1], Wp, bp, We1, be1,
                                  We2, be2, We3, be3, Ws1, bs1, Ws2, bs2, Ws3, bs3, outv);
}

extern "C" void kernel_launch(void* const* d_in, const int* in_sizes, int n_in,
                              void* d_out, int out_size, void* d_ws, size_t ws_size,
                              hipStream_t stream) {
  const void* x      = d_in[0];
  const void* distsq = d_in[1];
  const int*  nidx   = (const int*)d_in[2];

  float* w = (float*)d_ws;
  int* flags = (int*)(w + FLAGS_OFF);
  int n_nodes = in_sizes[0] / F_IN;

  size_t need = (size_t)STAGE_OFF * 4 + (size_t)n_nodes * 64 + (size_t)n_nodes * 4 + 256;
  if (ws_size >= need) {
    setupK<<<32, 256, 0, stream>>>((const ushort*)x, nidx,
                                   d_in[3], d_in[4], d_in[5], d_in[6], d_in[7], d_in[8],
                                   d_in[9], d_in[10], d_in[11], d_in[12], d_in[13], d_in[14],
                                   d_in[15], d_in[16], w);
    ushort* xp = (ushort*)(w + STAGE_OFF);
    float* xs = (float*)(xp + (size_t)n_nodes * 32);
    preK<<<2048, 256, 0, stream>>>(x, w, flags, xp, xs, n_nodes);
    edgeK<<<1024, 256, 0, stream>>>(xp, xs, distsq, nidx, w, flags, d_out, n_nodes);
  } else {
    int grid = (n_nodes + 255) / 256;
    fused<<<grid, 256, 0, stream>>>(x, distsq, nidx, d_in[3], d_in[4], d_in[5], d_in[6],
                                    d_in[7], d_in[8], d_in[9], d_in[10], d_in[11], d_in[12],
                                    d_in[13], d_in[14], d_in[15], d_in[16], d_out, n_nodes);
  }
}

// Round 4
// 249.703 us; speedup vs baseline: 1.3088x; 1.3088x over previous
//
#include <hip/hip_runtime.h>
#include <hip/hip_bf16.h>
#include <math.h>

typedef __hip_bfloat16 bf16;
typedef __attribute__((ext_vector_type(8))) __bf16 bf16x8;
typedef __attribute__((ext_vector_type(4))) float f32x4;
typedef unsigned int u32x4 __attribute__((ext_vector_type(4)));
typedef unsigned int u32x2 __attribute__((ext_vector_type(2)));

#define F_IN 64
#define KNB 6

// ws float offsets: biases + flags + frag blobs; staged xp/xs after STAGE_OFF
#define WOFF_BP   2048   // 32
#define WOFF_BE2  9472   // 32
#define WOFF_BE3  9696   // 6
#define WOFF_BS1  11776  // 32
#define WOFF_BS2  12832  // 32
#define WOFF_BS3  12896  // 1
#define FLAGS_OFF 13056  // int[2]: {is_bf16, is_int64}
#define FRAG_OFF  14592  // 30 frags * 256 floats = 7680 -> ends 22272
#define NFRAG_PRE 11
#define NFRAG_EDGE 19
#define STAGE_OFF 24576  // floats; then xp bf16 rows, then xs fp32

#define MFMA(a, b, c) __builtin_amdgcn_mfma_f32_16x16x32_bf16(a, b, c, 0, 0, 0)

__device__ __forceinline__ float b2f(bf16 v) { return __bfloat162float(v); }
// fast ELU via hardware exp; abs err ~1e-7 near 0, far under tol
__device__ __forceinline__ float eluf(float v) { return v > 0.f ? v : __expf(v) - 1.f; }

__device__ __forceinline__ ushort f2bu(float v) {
  __bf16 b = (__bf16)v; ushort u; __builtin_memcpy(&u, &b, 2); return u;
}

union U8 { uint4 u; bf16x8 v; ushort s[8]; };

// non-temporal loads (read-once streaming data; keep L2/L3 for xp gathers)
__device__ __forceinline__ uint4 ntload16(const void* p) {
  u32x4 t = __builtin_nontemporal_load((const u32x4*)p);
  uint4 r; r.x = t.x; r.y = t.y; r.z = t.z; r.w = t.w; return r;
}
__device__ __forceinline__ uint2 ntload8(const void* p) {
  u32x2 t = __builtin_nontemporal_load((const u32x2*)p);
  uint2 r; r.x = t.x; r.y = t.y; return r;
}

// read one staged weight A-fragment (1KB blob: lane*16B) from LDS
__device__ __forceinline__ bf16x8 ldfrag(const ushort* fr, int f) {
  U8 u; u.u = *(const uint4*)(fr + f * 512 + (threadIdx.x & 63) * 8);
  return u.v;
}

// permuted output-feature index: C row m' of half t holds original feature o.
// Makes the transposed-MFMA C layout coincide with the next layer's B-frag layout.
__device__ __forceinline__ int permo(int m, int t) { return 8 * (m >> 2) + (m & 3) + 4 * t; }

// ==================== setup: flags + bias staging + frag build (parallel, raw-source) ====================
__global__ void setupK(const ushort* xb, const int* ni,
                       const void* Wp, const void* bp, const void* We1, const void* be1,
                       const void* We2, const void* be2, const void* We3, const void* be3,
                       const void* Ws1, const void* bs1, const void* Ws2, const void* bs2,
                       const void* Ws3, const void* bs3, float* w) {
  __shared__ int sbf;
  int t = threadIdx.x;
  // per-block dtype detect (cheap, L2-hot): fp32 bits read as bf16 halves are wild
  if (t < 64) {
    int bad = 0;
    for (int i = t; i < 256; i += 64) {
      float v = __uint_as_float(((unsigned)xb[i]) << 16);
      if (!(fabsf(v) < 100.f)) bad++;
    }
    unsigned long long bm = __ballot(bad > 0);
    if (t == 0) sbf = (__popcll(bm) < 4) ? 1 : 0;
  }
  __syncthreads();
  int bf = sbf;
  auto rv = [&](const void* p, long i) -> float {
    return bf ? b2f(((const bf16*)p)[i]) : ((const float*)p)[i];
  };
  if (blockIdx.x == 0) {
    if (t < 64) {
      unsigned long long hm = __ballot(ni[2 * t + 1] != 0);
      if (t == 0) {
        ((int*)(w + FLAGS_OFF))[0] = bf;
        ((int*)(w + FLAGS_OFF))[1] = (hm == 0ULL) ? 1 : 0;
      }
    }
    const void* bsrc[6] = {bp, bs1, bs2, bs3, be2, be3};
    const int bn[6] = {32, 32, 32, 1, 32, 6};
    const int bo[6] = {WOFF_BP, WOFF_BS1, WOFF_BS2, WOFF_BS3, WOFF_BE2, WOFF_BE3};
    for (int a = 0; a < 6; a++)
      for (int i = t; i < bn[a]; i += blockDim.x)
        w[bo[a] + i] = rv(bsrc[a], i);
  }
  // Frag element layout: blob[lane*8 + j] = A[m=lane&15][k=8*(lane>>4)+j].
  // ids: 0..3 P[s][t], 4..7 S1[s][t], 8..9 S2[t], 10 S3,
  //      11..22 E1[kn][t] (negated), 23..24 ESUM[t], 25..26 EDSQ[t] (+be1 row),
  //      27..28 E2[t], 29 E3
  ushort* fbv = (ushort*)(w + FRAG_OFF);
  int total = (NFRAG_PRE + NFRAG_EDGE) * 512;
  for (int i = blockIdx.x * blockDim.x + t; i < total; i += gridDim.x * blockDim.x) {
    int f = i >> 9, e = i & 511;
    int lane = e >> 3, j = e & 7;
    int mm = lane & 15, qq = lane >> 4;
    int k = qq * 8 + j;
    float v = 0.f;
    if (f < 4) { int s = f >> 1, tt = f & 1; v = rv(Wp, (long)(32 * s + k) * 32 + permo(mm, tt)); }
    else if (f < 8) { int s = (f - 4) >> 1, tt = f & 1; v = rv(Ws1, (long)(32 * s + k) * 32 + permo(mm, tt)); }
    else if (f < 10) { int tt = f & 1; v = rv(Ws2, (long)k * 32 + permo(mm, tt)); }
    else if (f == 10) { v = (mm == 0) ? rv(Ws3, k) : 0.f; }
    else if (f < 23) { int kn = (f - 11) >> 1, tt = (f - 11) & 1;
                       v = -rv(We1, (long)(kn * 33 + k) * 32 + permo(mm, tt)); }
    else if (f < 25) { int tt = f - 23; float s = 0.f;
#pragma unroll
                       for (int kn = 0; kn < KNB; kn++)
                         s += rv(We1, (long)(kn * 33 + k) * 32 + permo(mm, tt));
                       v = s; }
    else if (f < 27) { int tt = f - 25; int o = permo(mm, tt);
                       v = (k < 6) ? rv(We1, (long)(k * 33 + 32) * 32 + o)
                                   : (k == 6 ? rv(be1, o) : 0.f); }
    else if (f < 29) { int tt = f - 27; v = rv(We2, (long)k * 32 + permo(mm, tt)); }
    else { v = (mm < KNB) ? rv(We3, (long)k * 6 + mm) : 0.f; }
    fbv[i] = f2bu(v);
  }
}

// ==================== kernel A: pre-dense + self MLP (transposed MFMA, no LDS data) ====================
template <bool BF16>
__device__ void pre_tiles(const void* xv, const float* __restrict__ w,
                          ushort* __restrict__ xp, float* __restrict__ xs,
                          int n_nodes, const ushort* __restrict__ fr) {
  int lane = threadIdx.x & 63;
  int m = lane & 15, q = lane >> 4;
  float bp8[8], bs18[8], bs28[8];
#pragma unroll
  for (int j = 0; j < 8; j++) {
    bp8[j]  = w[WOFF_BP  + 8 * q + j];
    bs18[j] = w[WOFF_BS1 + 8 * q + j];
    bs28[j] = w[WOFF_BS2 + 8 * q + j];
  }
  float bs3 = w[WOFF_BS3];
  long T = ((long)n_nodes + 15) >> 4;
  long wid = (long)((blockIdx.x * blockDim.x + threadIdx.x) >> 6);
  long nw = (long)((gridDim.x * blockDim.x) >> 6);
  f32x4 zero = {0.f, 0.f, 0.f, 0.f};

  uint4 bufA[4], bufB[4];
  auto loadraw = [&](uint4* r, long tt) {
    long row = tt * 16 + m; if (row >= n_nodes) row = n_nodes - 1;
    if (BF16) {
      const ushort* p = (const ushort*)xv + row * F_IN + q * 8;
      r[0] = ntload16(p);
      r[1] = ntload16(p + 32);
    } else {
      const float* p = (const float*)xv + row * F_IN + q * 8;
      r[0] = ntload16(p);      r[1] = ntload16(p + 4);
      r[2] = ntload16(p + 32); r[3] = ntload16(p + 36);
    }
  };
  auto mkfrag = [&](const uint4* r, int s) -> bf16x8 {
    if (BF16) { U8 u; u.u = r[s]; return u.v; }
    float f0[8];
    __builtin_memcpy(f0, r + 2 * s, 32);
    bf16x8 out;
#pragma unroll
    for (int j = 0; j < 8; j++) out[j] = (__bf16)f0[j];
    return out;
  };
  auto body = [&](uint4* cur, uint4* nxt, long t) {
    long tn = t + nw;
    if (tn < T) loadraw(nxt, tn);            // prefetch next tile's x
    long n0 = t * 16;
    long row = n0 + m; if (row >= n_nodes) row = n_nodes - 1;
    bf16x8 x0 = mkfrag(cur, 0), x1 = mkfrag(cur, 1);
    f32x4 aP[2], aS[2];
    __builtin_amdgcn_s_setprio(1);
#pragma unroll
    for (int tt = 0; tt < 2; tt++) {
      aP[tt] = MFMA(ldfrag(fr, 0 + tt), x0, zero);
      aP[tt] = MFMA(ldfrag(fr, 2 + tt), x1, aP[tt]);
      aS[tt] = MFMA(ldfrag(fr, 4 + tt), x0, zero);
      aS[tt] = MFMA(ldfrag(fr, 6 + tt), x1, aS[tt]);
    }
    __builtin_amdgcn_s_setprio(0);
    // xp row store straight from registers: lane holds features 8q..8q+7 of its node
    U8 o1;
#pragma unroll
    for (int j = 0; j < 8; j++) o1.s[j] = f2bu(eluf(aP[j >> 2][j & 3] + bp8[j]));
    *(uint4*)(xp + row * 32 + q * 8) = o1.u;
    bf16x8 s1e;
#pragma unroll
    for (int j = 0; j < 8; j++) s1e[j] = (__bf16)eluf(aS[j >> 2][j & 3] + bs18[j]);
    f32x4 a2[2];
#pragma unroll
    for (int tt = 0; tt < 2; tt++) a2[tt] = MFMA(ldfrag(fr, 8 + tt), s1e, zero);
    bf16x8 s2e;
#pragma unroll
    for (int j = 0; j < 8; j++) s2e[j] = (__bf16)eluf(a2[j >> 2][j & 3] + bs28[j]);
    f32x4 a3 = MFMA(ldfrag(fr, 10), s2e, zero);
    if (q == 0) {
      long orow = n0 + m;
      if (orow < n_nodes) xs[orow] = a3[0] + bs3;
    }
  };
  long t = wid;
  if (t < T) loadraw(bufA, t);
  while (t < T) {
    body(bufA, bufB, t);
    t += nw; if (t >= T) break;
    body(bufB, bufA, t);
    t += nw;
  }
}

__launch_bounds__(256)
__global__ void preK(const void* xv, const float* __restrict__ w,
                     const int* __restrict__ flags,
                     ushort* __restrict__ xp, float* __restrict__ xs, int n_nodes) {
  __shared__ uint4 fsh[NFRAG_PRE * 64];
  const uint4* fbv = (const uint4*)((const ushort*)(w + FRAG_OFF));
  for (int i = threadIdx.x; i < NFRAG_PRE * 64; i += blockDim.x) fsh[i] = fbv[i];
  __syncthreads();
  const ushort* fr = (const ushort*)fsh;
  if (flags[0]) pre_tiles<true>(xv, w, xp, xs, n_nodes, fr);
  else          pre_tiles<false>(xv, w, xp, xs, n_nodes, fr);
}

// ==================== kernel B: edge MLP + softmax (transposed MFMA, depth-2 pipeline) ====================
struct ETile { U8 nb[KNB]; U8 own; U8 ad; float xsv; };

template <bool BF16>
__device__ void edge_tiles(const ushort* __restrict__ xp, const float* __restrict__ xs,
                           const void* dsv, const int* __restrict__ ni, int i64,
                           const float* __restrict__ w, void* outv, int n_nodes,
                           const ushort* __restrict__ fr) {
  int lane = threadIdx.x & 63;
  int m = lane & 15, q = lane >> 4;
  float b2[8], b3[4];
#pragma unroll
  for (int j = 0; j < 8; j++) b2[j] = w[WOFF_BE2 + 8 * q + j];
#pragma unroll
  for (int r = 0; r < 4; r++) { int o = 4 * q + r; b3[r] = (o < 6) ? w[WOFF_BE3 + o] : 0.f; }

  long T = ((long)n_nodes + 15) >> 4;
  long wid = (long)((blockIdx.x * blockDim.x + threadIdx.x) >> 6);
  long nw = (long)((gridDim.x * blockDim.x) >> 6);
  f32x4 zero = {0.f, 0.f, 0.f, 0.f};
  ETile A, B;
  int Ia[KNB], Ib[KNB];

  // neighbor indices for tile tt (vectorized, non-temporal; used one body later)
  auto pidx = [&](int* ix, long tt) {
    long row = tt * 16 + m; if (row >= n_nodes) row = n_nodes - 1;
    if (i64) {
      const uint4* p = (const uint4*)((const char*)ni + row * (KNB * 8));  // 16B aligned
      uint4 a = ntload16(p), b = ntload16(p + 1), c = ntload16(p + 2);
      ix[0] = (int)a.x; ix[1] = (int)a.z; ix[2] = (int)b.x;
      ix[3] = (int)b.z; ix[4] = (int)c.x; ix[5] = (int)c.z;
    } else {
      const uint2* p = (const uint2*)((const char*)ni + row * (KNB * 4));  // 8B aligned
      uint2 a = ntload8(p), b = ntload8(p + 1), c = ntload8(p + 2);
      ix[0] = (int)a.x; ix[1] = (int)a.y; ix[2] = (int)b.x;
      ix[3] = (int)b.y; ix[4] = (int)c.x; ix[5] = (int)c.y;
    }
  };
  // streaming per-node loads (own xp row, distsq, xs)
  auto phead = [&](ETile& d, long tt) {
    long row = tt * 16 + m; if (row >= n_nodes) row = n_nodes - 1;
    d.own.u = *(const uint4*)(xp + row * 32 + q * 8);
    d.ad.u.x = 0; d.ad.u.y = 0; d.ad.u.z = 0; d.ad.u.w = 0;
    if (q == 0) {
      if (BF16) {
        const unsigned* dp = (const unsigned*)dsv;
        d.ad.u.x = dp[row * 3 + 0]; d.ad.u.y = dp[row * 3 + 1]; d.ad.u.z = dp[row * 3 + 2];
      } else {
        const uint2* dp = (const uint2*)((const char*)dsv + row * (KNB * 4));
        uint2 a = ntload8(dp), b = ntload8(dp + 1), c = ntload8(dp + 2);
        d.ad.s[0] = f2bu(__uint_as_float(a.x)); d.ad.s[1] = f2bu(__uint_as_float(a.y));
        d.ad.s[2] = f2bu(__uint_as_float(b.x)); d.ad.s[3] = f2bu(__uint_as_float(b.y));
        d.ad.s[4] = f2bu(__uint_as_float(c.x)); d.ad.s[5] = f2bu(__uint_as_float(c.y));
      }
      d.ad.s[6] = 0x3F80u;  // 1.0bf16: multiplies the be1 row baked into EDSQ frag
    }
    d.xsv = xs[row];
  };
  // dependent random gathers (indices issued one full body earlier)
  auto pgather = [&](ETile& d, const int* ix) {
#pragma unroll
    for (int k = 0; k < KNB; k++) {
      int v = ix[k];
      long ai = (v < 0 || v >= n_nodes) ? 0 : (long)v;
      uint4 g = *(const uint4*)(xp + ai * 32 + q * 8);
      if (v < 0) { g.x = 0; g.y = 0; g.z = 0; g.w = 0; }
      d.nb[k].u = g;
    }
  };
  auto iterb = [&](ETile& cur, ETile& nxt, int* Iin, int* Iout, long t) {
    long t2 = t + 2 * nw;
    bool h2 = t2 < T;
    if (h2) pidx(Iout, t2);                 // indices two tiles ahead
    // layer 1: h1^T = ESUM*own + EDSQ*[dsq,1] + sum_k (-E1k)*nb_k (be1 folded in EDSQ)
    f32x4 acc[2];
    __builtin_amdgcn_s_setprio(1);
#pragma unroll
    for (int tt = 0; tt < 2; tt++) {
      acc[tt] = MFMA(ldfrag(fr, 12 + tt), cur.own.v, zero);
      acc[tt] = MFMA(ldfrag(fr, 14 + tt), cur.ad.v, acc[tt]);
#pragma unroll
      for (int k = 0; k < KNB; k++)
        acc[tt] = MFMA(ldfrag(fr, k * 2 + tt), cur.nb[k].v, acc[tt]);
    }
    __builtin_amdgcn_s_setprio(0);
    if (t + nw < T) pgather(nxt, Iin);      // idx landed during previous body
    // layers 2/3 entirely in registers (perm baked into frags)
    bf16x8 a1;
#pragma unroll
    for (int j = 0; j < 8; j++) a1[j] = (__bf16)eluf(acc[j >> 2][j & 3]);
    f32x4 acc2[2];
    __builtin_amdgcn_s_setprio(1);
#pragma unroll
    for (int tt = 0; tt < 2; tt++) acc2[tt] = MFMA(ldfrag(fr, 16 + tt), a1, zero);
    __builtin_amdgcn_s_setprio(0);
    bf16x8 a2;
#pragma unroll
    for (int j = 0; j < 8; j++) a2[j] = (__bf16)eluf(acc2[j >> 2][j & 3] + b2[j]);
    f32x4 a3 = MFMA(ldfrag(fr, 18), a2, zero);
    float l0 = a3[0] + b3[0], l1 = a3[1] + b3[1], l2 = a3[2] + b3[2], l3 = a3[3] + b3[3];
    // quad1 holds logits 4,5 for the same node; pull them to quad0
    float o4 = __shfl(l0, m + 16, 64);
    float o5 = __shfl(l1, m + 16, 64);
    if (lane < 16) {
      long nodeid = t * 16 + lane;
      if (nodeid < n_nodes) {
        float lg[7] = {cur.xsv, l0, l1, l2, l3, o4, o5};
        float mx = lg[0];
#pragma unroll
        for (int i = 1; i < 7; i++) mx = fmaxf(mx, lg[i]);
        float e[7], ssum = 0.f;
#pragma unroll
        for (int i = 0; i < 7; i++) { e[i] = __expf(lg[i] - mx); ssum += e[i]; }
        float inv = 1.f / ssum;
        if (BF16) {
          ushort* o = (ushort*)outv + nodeid * 7;
#pragma unroll
          for (int i = 0; i < 7; i++) __builtin_nontemporal_store(f2bu(e[i] * inv), o + i);
        } else {
          float* o = (float*)outv + nodeid * 7;
#pragma unroll
          for (int i = 0; i < 7; i++) __builtin_nontemporal_store(e[i] * inv, o + i);
        }
      }
    }
    if (h2) phead(cur, t2);                 // reuse cur slot: head of tile t+2
  };
  long t = wid;
  if (t < T) {
    pidx(Ia, t); phead(A, t); pgather(A, Ia);
    if (t + nw < T) { pidx(Ia, t + nw); phead(B, t + nw); }
  }
  while (t < T) {
    iterb(A, B, Ia, Ib, t);
    t += nw; if (t >= T) break;
    iterb(B, A, Ib, Ia, t);
    t += nw;
  }
}

__launch_bounds__(256)
__global__ void edgeK(const ushort* __restrict__ xp, const float* __restrict__ xs,
                      const void* dsv, const int* __restrict__ ni,
                      const float* __restrict__ w, const int* __restrict__ flags,
                      void* outv, int n_nodes) {
  __shared__ uint4 fsh[NFRAG_EDGE * 64];
  const uint4* fbv = (const uint4*)((const ushort*)(w + FRAG_OFF) + NFRAG_PRE * 512);
  for (int i = threadIdx.x; i < NFRAG_EDGE * 64; i += blockDim.x) fsh[i] = fbv[i];
  __syncthreads();
  const ushort* fr = (const ushort*)fsh;
  if (flags[0]) edge_tiles<true>(xp, xs, dsv, ni, flags[1], w, outv, n_nodes, fr);
  else          edge_tiles<false>(xp, xs, dsv, ni, flags[1], w, outv, n_nodes, fr);
}

// ==================== fallback path (small ws) ====================
template <bool BF16>
__device__ __forceinline__ float wval(const void* W, long i) {
  if (BF16) return b2f(((const bf16*)W)[i]);
  return ((const float*)W)[i];
}

__device__ __forceinline__ void block_flags(const ushort* xb, const int* ni, int* sflags) {
  if (threadIdx.x < 64) {
    int t = threadIdx.x;
    int bad = 0;
    for (int i = t; i < 256; i += 64) {
      float v = __uint_as_float(((unsigned)xb[i]) << 16);
      if (!(fabsf(v) < 100.f)) bad++;
    }
    unsigned long long bm = __ballot(bad > 0);
    unsigned long long hm = __ballot(ni[2 * t + 1] != 0);
    if (t == 0) {
      sflags[0] = (__popcll(bm) < 4) ? 1 : 0;
      sflags[1] = (hm == 0ULL) ? 1 : 0;
    }
  }
  __syncthreads();
}

template <bool BF16>
__device__ void node_body(int n, int n_nodes, const void* xv, const void* dsv,
                          const int* __restrict__ ni, int i64,
                          const void* Wp, const void* bp, const void* We1, const void* be1,
                          const void* We2, const void* be2, const void* We3, const void* be3,
                          const void* Ws1, const void* bs1, const void* Ws2, const void* bs2,
                          const void* Ws3, const void* bs3, void* outv) {
  float h[32], s1[32];
#pragma unroll
  for (int o = 0; o < 32; o++) { h[o] = wval<BF16>(bp, o); s1[o] = wval<BF16>(bs1, o); }
  for (int j = 0; j < F_IN; j++) {
    float xj = wval<BF16>(xv, (long)n * F_IN + j);
#pragma unroll
    for (int o = 0; o < 32; o++) {
      h[o]  += xj * wval<BF16>(Wp,  (long)j * 32 + o);
      s1[o] += xj * wval<BF16>(Ws1, (long)j * 32 + o);
    }
  }
  float own[32];
#pragma unroll
  for (int o = 0; o < 32; o++) own[o] = eluf(h[o]);
  float s2[32];
#pragma unroll
  for (int o = 0; o < 32; o++) s2[o] = wval<BF16>(bs2, o);
  for (int j = 0; j < 32; j++) {
    float v = eluf(s1[j]);
#pragma unroll
    for (int o = 0; o < 32; o++) s2[o] += v * wval<BF16>(Ws2, (long)j * 32 + o);
  }
  float xsv = wval<BF16>(bs3, 0);
#pragma unroll
  for (int j = 0; j < 32; j++) xsv += eluf(s2[j]) * wval<BF16>(Ws3, j);

  float h1[32];
#pragma unroll
  for (int o = 0; o < 32; o++) h1[o] = wval<BF16>(be1, o);
  for (int k = 0; k < KNB; k++) {
    long pos = (long)n * KNB + k;
    int idx = i64 ? ni[2 * pos] : ni[pos];
    float mmask = idx < 0 ? 0.f : 1.f;
    long ai = idx < 0 ? 0 : idx;
    if (ai >= n_nodes) ai = 0;
    float nh[32];
#pragma unroll
    for (int o = 0; o < 32; o++) nh[o] = wval<BF16>(bp, o);
    for (int j = 0; j < F_IN; j++) {
      float xj = wval<BF16>(xv, ai * F_IN + j);
#pragma unroll
      for (int o = 0; o < 32; o++) nh[o] += xj * wval<BF16>(Wp, (long)j * 32 + o);
    }
#pragma unroll
    for (int j = 0; j < 32; j++) {
      float d = own[j] - mmask * eluf(nh[j]);
#pragma unroll
      for (int o = 0; o < 32; o++) h1[o] += d * wval<BF16>(We1, ((long)(k * 33 + j)) * 32 + o);
    }
    float dsq = BF16 ? b2f(((const bf16*)dsv)[pos]) : ((const float*)dsv)[pos];
#pragma unroll
    for (int o = 0; o < 32; o++) h1[o] += dsq * wval<BF16>(We1, ((long)(k * 33 + 32)) * 32 + o);
  }
  float h2[32];
#pragma unroll
  for (int o = 0; o < 32; o++) h2[o] = wval<BF16>(be2, o);
  for (int j = 0; j < 32; j++) {
    float v = eluf(h1[j]);
#pragma unroll
    for (int o = 0; o < 32; o++) h2[o] += v * wval<BF16>(We2, (long)j * 32 + o);
  }
  float lg[7];
  lg[0] = xsv;
#pragma unroll
  for (int o = 0; o < 6; o++) lg[1 + o] = wval<BF16>(be3, o);
  for (int j = 0; j < 32; j++) {
    float v = eluf(h2[j]);
#pragma unroll
    for (int o = 0; o < 6; o++) lg[1 + o] += v * wval<BF16>(We3, (long)j * 6 + o);
  }
  float mx = lg[0];
#pragma unroll
  for (int i = 1; i < 7; i++) mx = fmaxf(mx, lg[i]);
  float e[7], ssum = 0.f;
#pragma unroll
  for (int i = 0; i < 7; i++) { e[i] = __expf(lg[i] - mx); ssum += e[i]; }
  float inv = 1.f / ssum;
  if (BF16) {
    bf16* o = (bf16*)outv;
#pragma unroll
    for (int i = 0; i < 7; i++) o[(long)n * 7 + i] = __float2bfloat16(e[i] * inv);
  } else {
    float* o = (float*)outv;
#pragma unroll
    for (int i = 0; i < 7; i++) o[(long)n * 7 + i] = e[i] * inv;
  }
}

__launch_bounds__(256)
__global__ void fused(const void* xv, const void* dsv, const int* __restrict__ ni,
                      const void* Wp, const void* bp, const void* We1, const void* be1,
                      const void* We2, const void* be2, const void* We3, const void* be3,
                      const void* Ws1, const void* bs1, const void* Ws2, const void* bs2,
                      const void* Ws3, const void* bs3, void* outv, int n_nodes) {
  __shared__ int sflags[2];
  block_flags((const ushort*)xv, ni, sflags);
  int n = blockIdx.x * blockDim.x + threadIdx.x;
  if (n >= n_nodes) return;
  if (sflags[0]) node_body<true>(n, n_nodes, xv, dsv, ni, sflags[1], Wp, bp, We1, be1,
                                 We2, be2, We3, be3, Ws1, bs1, Ws2, bs2, Ws3, bs3, outv);
  else           node_body<false>(n, n_nodes, xv, dsv, ni, sflags[1], Wp, bp, We1, be1,
                                  We2, be2, We3, be3, Ws1, bs1, Ws2, bs2, Ws3, bs3, outv);
}

extern "C" void kernel_launch(void* const* d_in, const int* in_sizes, int n_in,
                              void* d_out, int out_size, void* d_ws, size_t ws_size,
                              hipStream_t stream) {
  const void* x      = d_in[0];
  const void* distsq = d_in[1];
  const int*  nidx   = (const int*)d_in[2];

  float* w = (float*)d_ws;
  int* flags = (int*)(w + FLAGS_OFF);
  int n_nodes = in_sizes[0] / F_IN;

  size_t need = (size_t)STAGE_OFF * 4 + (size_t)n_nodes * 64 + (size_t)n_nodes * 4 + 256;
  if (ws_size >= need) {
    setupK<<<32, 256, 0, stream>>>((const ushort*)x, nidx,
                                   d_in[3], d_in[4], d_in[5], d_in[6], d_in[7], d_in[8],
                                   d_in[9], d_in[10], d_in[11], d_in[12], d_in[13], d_in[14],
                                   d_in[15], d_in[16], w);
    ushort* xp = (ushort*)(w + STAGE_OFF);
    float* xs = (float*)(xp + (size_t)n_nodes * 32);
    preK<<<2048, 256, 0, stream>>>(x, w, flags, xp, xs, n_nodes);
    edgeK<<<1024, 256, 0, stream>>>(xp, xs, distsq, nidx, w, flags, d_out, n_nodes);
  } else {
    int grid = (n_nodes + 255) / 256;
    fused<<<grid, 256, 0, stream>>>(x, distsq, nidx, d_in[3], d_in[4], d_in[5], d_in[6],
                                    d_in[7], d_in[8], d_in[9], d_in[10], d_in[11], d_in[12],
                                    d_in[13], d_in[14], d_in[15], d_in[16], d_out, n_nodes);
  }
}